// Round 2
// baseline (207.733 us; speedup 1.0000x reference)
//
#include <hip/hip_runtime.h>
#include <stdint.h>
#include <math.h>

// ---------------------------------------------------------------------------
// Threefry-2x32 (JAX-compatible, 20 rounds)
// ---------------------------------------------------------------------------
#define TF_ROUND(r) do { x0 += x1; x1 = (x1 << (r)) | (x1 >> (32 - (r))); x1 ^= x0; } while (0)

__device__ __forceinline__ void threefry2x32(uint32_t k0, uint32_t k1,
                                             uint32_t x0, uint32_t x1,
                                             uint32_t& y0, uint32_t& y1)
{
    uint32_t k2 = k0 ^ k1 ^ 0x1BD11BDAu;
    x0 += k0; x1 += k1;
    TF_ROUND(13); TF_ROUND(15); TF_ROUND(26); TF_ROUND(6);
    x0 += k1; x1 += k2 + 1u;
    TF_ROUND(17); TF_ROUND(29); TF_ROUND(16); TF_ROUND(24);
    x0 += k2; x1 += k0 + 2u;
    TF_ROUND(13); TF_ROUND(15); TF_ROUND(26); TF_ROUND(6);
    x0 += k0; x1 += k1 + 3u;
    TF_ROUND(17); TF_ROUND(29); TF_ROUND(16); TF_ROUND(24);
    x0 += k1; x1 += k2 + 4u;
    TF_ROUND(13); TF_ROUND(15); TF_ROUND(26); TF_ROUND(6);
    y0 = x0 + k2; y1 = x1 + k0 + 5u;
}

// ---------------------------------------------------------------------------
// Depthwise 3x3 stride-2 pad-1 conv. One block per (n,c) plane.
// Optionally applies y = relu(x*A + B) to the input while staging to LDS
// (BN+ReLU of the previous layer). Emits per-block sum/sumsq partials (f64).
// ---------------------------------------------------------------------------
template<int HIN, int HOUT, bool PRE_BN>
__global__ __launch_bounds__(256) void dw_kernel(
    const float* __restrict__ in, const float* __restrict__ wts,
    const float2* __restrict__ stats, float* __restrict__ out,
    double* __restrict__ psum, int C)
{
    __shared__ float tile[HIN * HIN];
    __shared__ double red[512];
    const int tid = threadIdx.x;
    const int blk = blockIdx.x;
    const int n = blk / C;
    const int c = blk - n * C;
    const float* ip = in + (size_t)(n * C + c) * (HIN * HIN);

    float A = 1.f, Bc = 0.f;
    if (PRE_BN) { float2 s = stats[c]; A = s.x; Bc = s.y; }
    for (int i = tid; i < HIN * HIN; i += 256) {
        float v = ip[i];
        if (PRE_BN) v = fmaxf(fmaf(v, A, Bc), 0.f);
        tile[i] = v;
    }
    float w9[9];
#pragma unroll
    for (int k = 0; k < 9; ++k) w9[k] = wts[c * 9 + k];
    __syncthreads();

    double ls = 0.0, lq = 0.0;
    float* op = out + (size_t)(n * C + c) * (HOUT * HOUT);
    for (int o = tid; o < HOUT * HOUT; o += 256) {
        const int oh = o / HOUT, ow = o - oh * HOUT;
        float acc = 0.f;
#pragma unroll
        for (int kh = 0; kh < 3; ++kh) {
            const int ih = 2 * oh - 1 + kh;
            if (ih < 0 || ih >= HIN) continue;
#pragma unroll
            for (int kw = 0; kw < 3; ++kw) {
                const int iw = 2 * ow - 1 + kw;
                if (iw < 0 || iw >= HIN) continue;
                acc = fmaf(tile[ih * HIN + iw], w9[kh * 3 + kw], acc);
            }
        }
        op[o] = acc;
        ls += (double)acc;
        lq += (double)acc * (double)acc;
    }
    red[tid] = ls; red[256 + tid] = lq;
    __syncthreads();
    for (int s = 128; s > 0; s >>= 1) {
        if (tid < s) { red[tid] += red[tid + s]; red[256 + tid] += red[256 + tid + s]; }
        __syncthreads();
    }
    if (tid == 0) {
        psum[(size_t)c * 256 + n] = red[0];
        psum[(size_t)C * 256 + (size_t)c * 256 + n] = red[256];
    }
}

// ---------------------------------------------------------------------------
// Per-channel stats reduction: psum[c*NB + i] (sums) and psum[C*NB + c*NB + i]
// (sumsqs) -> stats[c] = (A, B) with bn(x) = x*A + B.
// ---------------------------------------------------------------------------
__global__ __launch_bounds__(256) void red_chan(
    const double* __restrict__ psum, int NB, double count,
    const float* __restrict__ g, const float* __restrict__ b,
    float2* __restrict__ stats, int C)
{
    __shared__ double red[512];
    const int c = blockIdx.x, tid = threadIdx.x;
    double s = 0.0, q = 0.0;
    for (int i = tid; i < NB; i += 256) {
        s += psum[(size_t)c * NB + i];
        q += psum[(size_t)C * NB + (size_t)c * NB + i];
    }
    red[tid] = s; red[256 + tid] = q;
    __syncthreads();
    for (int st = 128; st > 0; st >>= 1) {
        if (tid < st) { red[tid] += red[tid + st]; red[256 + tid] += red[256 + tid + st]; }
        __syncthreads();
    }
    if (tid == 0) {
        double mean = red[0] / count;
        double var = red[256] / count - mean * mean;
        double rstd = 1.0 / sqrt(var + 1e-5);
        double Ad = rstd * (double)g[c];
        double Bd = (double)b[c] - mean * Ad;
        stats[c] = make_float2((float)Ad, (float)Bd);
    }
}

// ---------------------------------------------------------------------------
// Pointwise 1x1 conv CIN->10, with BN+ReLU of input applied on the fly.
// One thread per output pixel position (n,sp); computes all 10 out channels.
// ---------------------------------------------------------------------------
template<int CIN, int S>
__global__ __launch_bounds__(256) void pw_kernel(
    const float* __restrict__ in, const float* __restrict__ wts,
    const float2* __restrict__ statsIn, float* __restrict__ out,
    double* __restrict__ psum)
{
    __shared__ float sw[10 * CIN];
    __shared__ float sA[CIN], sB[CIN];
    __shared__ double sred[2][4][16];
    const int tid = threadIdx.x;
    for (int i = tid; i < 10 * CIN; i += 256) sw[i] = wts[i];
    if (tid < CIN) { float2 s = statsIn[tid]; sA[tid] = s.x; sB[tid] = s.y; }
    __syncthreads();

    const int p = blockIdx.x * 256 + tid;
    const int n = p / S, sp = p - n * S;
    const float* ip = in + (size_t)n * CIN * S + sp;
    float acc[10];
#pragma unroll
    for (int oc = 0; oc < 10; ++oc) acc[oc] = 0.f;
    for (int c = 0; c < CIN; ++c) {
        float v = ip[(size_t)c * S];
        v = fmaxf(fmaf(v, sA[c], sB[c]), 0.f);
#pragma unroll
        for (int oc = 0; oc < 10; ++oc) acc[oc] = fmaf(v, sw[oc * CIN + c], acc[oc]);
    }
    float* op = out + (size_t)n * 10 * S + sp;
#pragma unroll
    for (int oc = 0; oc < 10; ++oc) op[(size_t)oc * S] = acc[oc];

    // deterministic block reduction: wave shuffle tree then 4-wave combine
    const int wid = tid >> 6, lane = tid & 63;
#pragma unroll
    for (int oc = 0; oc < 10; ++oc) {
        double s = (double)acc[oc];
        double q = (double)acc[oc] * (double)acc[oc];
        for (int off = 32; off > 0; off >>= 1) {
            s += __shfl_down(s, off);
            q += __shfl_down(q, off);
        }
        if (lane == 0) { sred[0][wid][oc] = s; sred[1][wid][oc] = q; }
    }
    __syncthreads();
    if (tid < 10) {
        double s = sred[0][0][tid] + sred[0][1][tid] + sred[0][2][tid] + sred[0][3][tid];
        double q = sred[1][0][tid] + sred[1][1][tid] + sred[1][2][tid] + sred[1][3][tid];
        psum[(size_t)tid * gridDim.x + blockIdx.x] = s;
        psum[(size_t)10 * gridDim.x + (size_t)tid * gridDim.x + blockIdx.x] = q;
    }
}

// ---------------------------------------------------------------------------
// feat = mean over 4x4 of relu(bn(x))   -> (256,10)
// ---------------------------------------------------------------------------
__global__ __launch_bounds__(256) void feat_kernel(
    const float* __restrict__ in, const float2* __restrict__ stats,
    float* __restrict__ feat)
{
    const int idx = blockIdx.x * 256 + threadIdx.x;
    if (idx >= 2560) return;
    const int n = idx / 10, c = idx - n * 10;
    const float* ip = in + (size_t)(n * 10 + c) * 16;
    const float2 st = stats[c];
    float s = 0.f;
#pragma unroll
    for (int i = 0; i < 16; ++i) s += fmaxf(fmaf(ip[i], st.x, st.y), 0.f);
    feat[idx] = s * 0.0625f;
}

// ---------------------------------------------------------------------------
// LSTM rollout + JAX-exact threefry/Gumbel categorical sampling.
// jax_threefry_partitionable=True semantics (JAX >= 0.4.36 default):
//   split(key,3):     key_i = threefry2x32(key, x0=0, x1=i)      (full pair)
//   random_bits(key): bits_f = y0 ^ y1, (y0,y1)=threefry2x32(key, 0, f)
// One block (64 lanes) per batch element.
// ---------------------------------------------------------------------------
__device__ __forceinline__ float sigf(float x) { return 0.5f + 0.5f * tanhf(0.5f * x); }

__global__ __launch_bounds__(64) void rollout_kernel(
    const float* __restrict__ feat,
    const float* __restrict__ wih0, const float* __restrict__ whh0,
    const float* __restrict__ bih0, const float* __restrict__ bhh0,
    const float* __restrict__ wih1, const float* __restrict__ whh1,
    const float* __restrict__ bih1, const float* __restrict__ bhh1,
    const float* __restrict__ head_w, const float* __restrict__ head_b,
    float* __restrict__ out)
{
    const int bb = blockIdx.x;   // batch element
    const int l = threadIdx.x;   // lane
    __shared__ float gum[2][19][6];
    __shared__ float s_inp[12], s_h0[10], s_h1[10], s_gates[40], s_logits[12];

    // ---- RNG precompute: key chain + all gumbels (data-independent) ----
    {
        uint32_t k0 = 0u, k1 = 1u;             // jax.random.key(1) -> (0,1)
        const uint32_t m = (uint32_t)(l < 3 ? l : 0);
        for (int t = 0; t < 19; ++t) {
            // foldlike split(key,3): key_i = threefry(key, 0, i), i = 0,1,2
            uint32_t y0, y1;
            threefry2x32(k0, k1, 0u, m, y0, y1);
            const uint32_t nk0 = (uint32_t)__shfl((int)y0, 0);
            const uint32_t nk1 = (uint32_t)__shfl((int)y1, 0);
            const uint32_t ka0 = (uint32_t)__shfl((int)y0, 1);
            const uint32_t ka1 = (uint32_t)__shfl((int)y1, 1);
            const uint32_t kw0 = (uint32_t)__shfl((int)y0, 2);
            const uint32_t kw1 = (uint32_t)__shfl((int)y1, 2);
            if (l < 12) {
                const int path = l / 6;            // 0 = action, 1 = w
                const int j = l - path * 6;
                const uint32_t kk0 = path ? kw0 : ka0;
                const uint32_t kk1 = path ? kw1 : ka1;
                const uint32_t flat = (uint32_t)(bb * 6 + j);  // index in (256,6)
                uint32_t z0, z1;
                threefry2x32(kk0, kk1, 0u, flat, z0, z1);
                const uint32_t bits = z0 ^ z1;     // partitionable 32-bit combine
                float u = __uint_as_float((bits >> 9) | 0x3f800000u) - 1.0f;
                if (u == 0.0f) u = 1.17549435e-38f;      // minval = f32 tiny
                const double l1 = log((double)u);        // log(u) (negative)
                gum[path][t][j] = (float)(-log(-l1));    // -log(-log(u))
            }
            k0 = nk0; k1 = nk1;
        }
    }

    // ---- weights into registers ----
    float wi0[12], wh0[10], bs0 = 0.f;
    float wi1[10], wh1[10], bs1 = 0.f;
    float hwr[10], hbr = 0.f;
    if (l < 40) {
#pragma unroll
        for (int k = 0; k < 12; ++k) wi0[k] = wih0[l * 12 + k];
#pragma unroll
        for (int k = 0; k < 10; ++k) wh0[k] = whh0[l * 10 + k];
        bs0 = bih0[l] + bhh0[l];
#pragma unroll
        for (int k = 0; k < 10; ++k) wi1[k] = wih1[l * 10 + k];
#pragma unroll
        for (int k = 0; k < 10; ++k) wh1[k] = whh1[l * 10 + k];
        bs1 = bih1[l] + bhh1[l];
    }
    if (l < 12) {
#pragma unroll
        for (int k = 0; k < 10; ++k) hwr[k] = head_w[l * 10 + k];
        hbr = head_b[l];
    }

    if (l < 12) s_inp[l] = (l < 10) ? feat[bb * 10 + l] : 0.f;
    if (l < 10) { s_h0[l] = 0.f; s_h1[l] = 0.f; }
    float c0 = 0.f, c1v = 0.f;
    __syncthreads();

    for (int t = 0; t < 19; ++t) {
        if (l < 40) {                                   // LSTM0 gates
            float gacc = bs0;
#pragma unroll
            for (int k = 0; k < 12; ++k) gacc = fmaf(s_inp[k], wi0[k], gacc);
#pragma unroll
            for (int k = 0; k < 10; ++k) gacc = fmaf(s_h0[k], wh0[k], gacc);
            s_gates[l] = gacc;
        }
        __syncthreads();
        if (l < 10) {                                   // LSTM0 cell update
            const float gi = s_gates[l], gf = s_gates[10 + l], gg = s_gates[20 + l], go = s_gates[30 + l];
            c0 = sigf(gf) * c0 + sigf(gi) * tanhf(gg);
            s_h0[l] = sigf(go) * tanhf(c0);
        }
        __syncthreads();
        if (l < 40) {                                   // LSTM1 gates
            float gacc = bs1;
#pragma unroll
            for (int k = 0; k < 10; ++k) gacc = fmaf(s_h0[k], wi1[k], gacc);
#pragma unroll
            for (int k = 0; k < 10; ++k) gacc = fmaf(s_h1[k], wh1[k], gacc);
            s_gates[l] = gacc;
        }
        __syncthreads();
        if (l < 10) {                                   // LSTM1 cell update
            const float gi = s_gates[l], gf = s_gates[10 + l], gg = s_gates[20 + l], go = s_gates[30 + l];
            c1v = sigf(gf) * c1v + sigf(gi) * tanhf(gg);
            s_h1[l] = sigf(go) * tanhf(c1v);
        }
        __syncthreads();
        if (l < 12) {                                   // head
            float v = hbr;
#pragma unroll
            for (int k = 0; k < 10; ++k) v = fmaf(s_h1[k], hwr[k], v);
            s_logits[l] = v;
        }
        __syncthreads();
        if (l < 2) {                                    // sample + log-softmax
            const float* lg = &s_logits[l * 6];
            const float* gm = &gum[l][t][0];
            int best = 0; float bv = lg[0] + gm[0];
#pragma unroll
            for (int j = 1; j < 6; ++j) { const float v = lg[j] + gm[j]; if (v > bv) { bv = v; best = j; } }
            float mx = lg[0];
#pragma unroll
            for (int j = 1; j < 6; ++j) mx = fmaxf(mx, lg[j]);
            float se = 0.f;
#pragma unroll
            for (int j = 0; j < 6; ++j) se += expf(lg[j] - mx);
            const float lp = (lg[best] - mx) - logf(se);
            out[l * 4864 + bb * 19 + t] = (float)(best + 2);        // bits (+2)
            out[9728 + l * 4864 + bb * 19 + t] = lp;                // log-probs
            s_inp[10 + l] = (float)best;                            // feedback
        }
        __syncthreads();
    }
}

// ---------------------------------------------------------------------------
extern "C" void kernel_launch(void* const* d_in, const int* in_sizes, int n_in,
                              void* d_out, int out_size, void* d_ws, size_t ws_size,
                              hipStream_t stream)
{
    const float* x      = (const float*)d_in[0];
    const float* dw0_w  = (const float*)d_in[1];
    const float* bn0a_g = (const float*)d_in[2];
    const float* bn0a_b = (const float*)d_in[3];
    const float* pw0_w  = (const float*)d_in[4];
    const float* bn0b_g = (const float*)d_in[5];
    const float* bn0b_b = (const float*)d_in[6];
    const float* dwr_w  = (const float*)d_in[7];
    const float* bnra_g = (const float*)d_in[8];
    const float* bnra_b = (const float*)d_in[9];
    const float* pwr_w  = (const float*)d_in[10];
    const float* bnrb_g = (const float*)d_in[11];
    const float* bnrb_b = (const float*)d_in[12];
    const float* wih0   = (const float*)d_in[13];
    const float* whh0   = (const float*)d_in[14];
    const float* bih0   = (const float*)d_in[15];
    const float* bhh0   = (const float*)d_in[16];
    const float* wih1   = (const float*)d_in[17];
    const float* whh1   = (const float*)d_in[18];
    const float* bih1   = (const float*)d_in[19];
    const float* bhh1   = (const float*)d_in[20];
    const float* head_w = (const float*)d_in[21];
    const float* head_b = (const float*)d_in[22];
    float* out = (float*)d_out;

    char* ws = (char*)d_ws;
    size_t off = 0;
    auto take = [&](size_t bytes) -> char* {
        char* p = ws + off;
        off += (bytes + 255) & ~(size_t)255;
        return p;
    };
    float* y0   = (float*)take(12845056ull * 4);  // (256,64,28,28)
    float* t1   = (float*)take(2007040ull * 4);   // (256,10,28,28)
    float* t2   = (float*)take(501760ull * 4);    // (256,10,14,14)
    float* t3   = (float*)take(501760ull * 4);
    float* t4   = (float*)take(125440ull * 4);    // (256,10,7,7)
    float* t5   = (float*)take(125440ull * 4);
    float* t6   = (float*)take(40960ull * 4);     // (256,10,4,4)
    float* t7   = (float*)take(40960ull * 4);
    float* feat = (float*)take(2560ull * 4);
    double* psum = (double*)take(32768ull * 8);
    float2* st0a = (float2*)take(64 * sizeof(float2));
    float2* st0b = (float2*)take(64 * sizeof(float2));
    float2* st1a = (float2*)take(64 * sizeof(float2));
    float2* st1b = (float2*)take(64 * sizeof(float2));
    float2* st2a = (float2*)take(64 * sizeof(float2));
    float2* st2b = (float2*)take(64 * sizeof(float2));
    float2* st3a = (float2*)take(64 * sizeof(float2));
    float2* st3b = (float2*)take(64 * sizeof(float2));

    // stage 0: 64ch dw conv 56->28, BN stats, pw 64->10, BN stats
    dw_kernel<56, 28, false><<<256 * 64, 256, 0, stream>>>(x, dw0_w, nullptr, y0, psum, 64);
    red_chan<<<64, 256, 0, stream>>>(psum, 256, 200704.0, bn0a_g, bn0a_b, st0a, 64);
    pw_kernel<64, 784><<<784, 256, 0, stream>>>(y0, pw0_w, st0a, t1, psum);
    red_chan<<<10, 256, 0, stream>>>(psum, 784, 200704.0, bn0b_g, bn0b_b, st0b, 10);
    // block 1: 28->14
    dw_kernel<28, 14, true><<<2560, 256, 0, stream>>>(t1, dwr_w + 0, st0b, t2, psum, 10);
    red_chan<<<10, 256, 0, stream>>>(psum, 256, 50176.0, bnra_g + 0, bnra_b + 0, st1a, 10);
    pw_kernel<10, 196><<<196, 256, 0, stream>>>(t2, pwr_w + 0, st1a, t3, psum);
    red_chan<<<10, 256, 0, stream>>>(psum, 196, 50176.0, bnrb_g + 0, bnrb_b + 0, st1b, 10);
    // block 2: 14->7
    dw_kernel<14, 7, true><<<2560, 256, 0, stream>>>(t3, dwr_w + 90, st1b, t4, psum, 10);
    red_chan<<<10, 256, 0, stream>>>(psum, 256, 12544.0, bnra_g + 10, bnra_b + 10, st2a, 10);
    pw_kernel<10, 49><<<49, 256, 0, stream>>>(t4, pwr_w + 100, st2a, t5, psum);
    red_chan<<<10, 256, 0, stream>>>(psum, 49, 12544.0, bnrb_g + 10, bnrb_b + 10, st2b, 10);
    // block 3: 7->4
    dw_kernel<7, 4, true><<<2560, 256, 0, stream>>>(t5, dwr_w + 180, st2b, t6, psum, 10);
    red_chan<<<10, 256, 0, stream>>>(psum, 256, 4096.0, bnra_g + 20, bnra_b + 20, st3a, 10);
    pw_kernel<10, 16><<<16, 256, 0, stream>>>(t6, pwr_w + 200, st3a, t7, psum);
    red_chan<<<10, 256, 0, stream>>>(psum, 16, 4096.0, bnrb_g + 20, bnrb_b + 20, st3b, 10);
    // feat + rollout
    feat_kernel<<<10, 256, 0, stream>>>(t7, st3b, feat);
    rollout_kernel<<<256, 64, 0, stream>>>(feat, wih0, whh0, bih0, bhh0,
                                           wih1, whh1, bih1, bhh1, head_w, head_b, out);
}